// Round 2
// 743.726 us; speedup vs baseline: 1.7117x; 1.7117x over previous
//
#include <hip/hip_runtime.h>
#include <stdint.h>

typedef __bf16 bf16;
typedef bf16 bf16x8 __attribute__((ext_vector_type(8)));
typedef bf16 bf16x4 __attribute__((ext_vector_type(4)));
typedef float f32x4 __attribute__((ext_vector_type(4)));

#define BROWS 16384
#define BM 128
#define BK 64
#define SL ((size_t)BROWS * 256)

__device__ __forceinline__ float sigmoidf_(float x) { return 1.0f / (1.0f + __expf(-x)); }
__device__ __forceinline__ float tanhf_(float x)    { return 1.0f - 2.0f / (1.0f + __expf(2.0f * x)); }

__device__ __forceinline__ bf16x4 cvt4(float4 v) {
    bf16x4 b; b[0] = (bf16)v.x; b[1] = (bf16)v.y; b[2] = (bf16)v.z; b[3] = (bf16)v.w;
    return b;
}

// Async global->LDS, 16B per lane. LDS dest = wave-uniform base + lane*16 (linear).
__device__ __forceinline__ void gload_lds16(const void* g, void* l) {
    __builtin_amdgcn_global_load_lds(
        (const __attribute__((address_space(1))) void*)g,
        (__attribute__((address_space(3))) void*)l, 16, 0, 0);
}

// ---------------------------------------------------------------------------
// Fast path: one-time fp32->bf16 conversion of x, h_all, weights (workspace),
// then pure-bf16 MFMA cells with global_load_lds staging + XOR swizzle.
// ---------------------------------------------------------------------------

__global__ void convert_all(
    const float* __restrict__ s0, bf16* __restrict__ d0, unsigned n0,
    const float* __restrict__ s1, bf16* __restrict__ d1, unsigned n1,
    const float* __restrict__ s2, bf16* __restrict__ d2, unsigned n2,
    const float* __restrict__ s3, bf16* __restrict__ d3, unsigned n3,
    const float* __restrict__ s4, bf16* __restrict__ d4, unsigned n4,
    const float* __restrict__ s5, bf16* __restrict__ d5, unsigned n5,
    const float* __restrict__ s6, bf16* __restrict__ d6, unsigned n6)
{
    const unsigned total = n0 + n1 + n2 + n3 + n4 + n5 + n6;
    const unsigned stride = gridDim.x * blockDim.x;
    for (unsigned i = blockIdx.x * blockDim.x + threadIdx.x; i < total; i += stride) {
        unsigned idx = i;
        const float* src; bf16* dst;
        if      (idx < n0)         { src = s0; dst = d0; }
        else if ((idx -= n0) < n1) { src = s1; dst = d1; }
        else if ((idx -= n1) < n2) { src = s2; dst = d2; }
        else if ((idx -= n2) < n3) { src = s3; dst = d3; }
        else if ((idx -= n3) < n4) { src = s4; dst = d4; }
        else if ((idx -= n4) < n5) { src = s5; dst = d5; }
        else                       { idx -= n5; src = s6; dst = d6; }
        float4 v = *(const float4*)(src + (size_t)idx * 4);
        *(bf16x4*)(dst + (size_t)idx * 4) = cvt4(v);
    }
}

// One LSTM cell, pure-bf16 operands. gates = A1@W1^T + A2@W2^T + (b1+b2).
// Gate-interleaved tile-col map: tile col t -> gate=(t>>4)&3,
// j = jblk + (t&15) + ((t>>6)<<4); weight row = gate*256 + j.
// Staging: global_load_lds width=16, linear LDS dest, inverse-XOR-swizzled
// per-lane GLOBAL source; ds_read applies the same XOR (rule #21).
__global__ __launch_bounds__(256, 4) void lstm_cell_bf16(
    const bf16* __restrict__ A1, const bf16* __restrict__ A2,
    const bf16* __restrict__ W1, const bf16* __restrict__ W2,
    const float* __restrict__ b1, const float* __restrict__ b2,
    const float* __restrict__ Cin,
    float* __restrict__ Hout, float* __restrict__ Cout,
    bf16* __restrict__ Hb)
{
    __shared__ __align__(16) bf16 As[BM * BK];
    __shared__ __align__(16) bf16 Bs[BM * BK];

    const int tid  = threadIdx.x;
    const int lane = tid & 63;
    const int wave = tid >> 6;
    const int wm   = wave >> 1;          // row half
    const int wn   = wave & 1;           // col half
    const int quad = lane >> 4;
    const int l15  = lane & 15;
    const int row0 = blockIdx.x * BM;
    const int jblk = blockIdx.y * 32;

    // staging lane geometry: each wave covers 8 rows x 8 slots (16B) per issue
    const int srow  = lane >> 3;         // row within the wave's 8-row group
    const int sslot = lane & 7;          // physical 16B slot this lane fills

    size_t aOff[4], bOff[4]; int ldsOff[4];
#pragma unroll
    for (int r4 = 0; r4 < 4; ++r4) {
        int rowT = r4 * 32 + wave * 8 + srow;
        int gsl  = (sslot ^ (rowT & 7)) * 8;          // inverse-swizzled source slot
        aOff[r4] = (size_t)(row0 + rowT) * 256 + gsl;
        int gate = (rowT >> 4) & 3;
        int j    = jblk + (rowT & 15) + ((rowT >> 6) << 4);
        bOff[r4] = (size_t)(gate * 256 + j) * 256 + gsl;
        ldsOff[r4] = (r4 * 32 + wave * 8) * BK;       // linear LDS dest (bf16 elems)
    }

    f32x4 acc[4][4];
#pragma unroll
    for (int i = 0; i < 4; ++i)
#pragma unroll
        for (int jj = 0; jj < 4; ++jj)
#pragma unroll
            for (int r = 0; r < 4; ++r) acc[i][jj][r] = 0.0f;

    for (int kIter = 0; kIter < 8; ++kIter) {
        const bf16* aSrc; const bf16* wSrc; int k0;
        if (kIter < 4) { aSrc = A1; wSrc = W1; k0 = kIter * BK; }
        else           { aSrc = A2; wSrc = W2; k0 = (kIter - 4) * BK; }

        __syncthreads();
#pragma unroll
        for (int r4 = 0; r4 < 4; ++r4)
            gload_lds16(aSrc + aOff[r4] + k0, &As[ldsOff[r4]]);
#pragma unroll
        for (int r4 = 0; r4 < 4; ++r4)
            gload_lds16(wSrc + bOff[r4] + k0, &Bs[ldsOff[r4]]);
        __syncthreads();   // compiler drains vmcnt(0) before s_barrier

#pragma unroll
        for (int kk = 0; kk < BK; kk += 32) {
            const int sl0 = (kk >> 3) + quad;         // logical 16B slot
            bf16x8 af[4], bfr[4];
#pragma unroll
            for (int mi = 0; mi < 4; ++mi) {
                int row = wm * 64 + mi * 16 + l15;
                int ps  = sl0 ^ (row & 7);            // swizzled read slot
                af[mi] = *(const bf16x8*)&As[row * BK + ps * 8];
            }
#pragma unroll
            for (int ni = 0; ni < 4; ++ni) {
                int row = wn * 64 + ni * 16 + l15;
                int ps  = sl0 ^ (row & 7);
                bfr[ni] = *(const bf16x8*)&Bs[row * BK + ps * 8];
            }
#pragma unroll
            for (int mi = 0; mi < 4; ++mi)
#pragma unroll
                for (int ni = 0; ni < 4; ++ni)
                    acc[mi][ni] = __builtin_amdgcn_mfma_f32_16x16x32_bf16(
                        af[mi], bfr[ni], acc[mi][ni], 0, 0, 0);
        }
    }

    // Epilogue: acc[mi][gate][reg] at row = row0+wm*64+mi*16+quad*4+reg, col j.
    const int j = jblk + wn * 16 + l15;
    float bsum[4];
#pragma unroll
    for (int g = 0; g < 4; ++g)
        bsum[g] = b1[g * 256 + j] + b2[g * 256 + j];

#pragma unroll
    for (int mi = 0; mi < 4; ++mi) {
#pragma unroll
        for (int reg = 0; reg < 4; ++reg) {
            int row = row0 + wm * 64 + mi * 16 + quad * 4 + reg;
            float gi = acc[mi][0][reg] + bsum[0];
            float gf = acc[mi][1][reg] + bsum[1];
            float gg = acc[mi][2][reg] + bsum[2];
            float go = acc[mi][3][reg] + bsum[3];
            float c  = Cin[(size_t)row * 256 + j];
            float cn = sigmoidf_(gf) * c + sigmoidf_(gi) * tanhf_(gg);
            float hn = sigmoidf_(go) * tanhf_(cn);
            Hout[(size_t)row * 256 + j] = hn;
            Cout[(size_t)row * 256 + j] = cn;
            Hb[(size_t)row * 256 + j]   = (bf16)hn;   // bf16 copy for next cell
        }
    }
}

// Out[B,256] = A[B,256] @ W[256,256]^T + bias, bf16 operands.
__global__ __launch_bounds__(256, 4) void linear_bf16(
    const bf16* __restrict__ A, const bf16* __restrict__ W,
    const float* __restrict__ bias, float* __restrict__ Out)
{
    __shared__ __align__(16) bf16 As[BM * BK];
    __shared__ __align__(16) bf16 Bs[BM * BK];

    const int tid  = threadIdx.x;
    const int lane = tid & 63;
    const int wave = tid >> 6;
    const int wm   = wave >> 1;
    const int wn   = wave & 1;
    const int quad = lane >> 4;
    const int l15  = lane & 15;
    const int row0 = blockIdx.x * BM;
    const int n0   = blockIdx.y * 128;

    const int srow  = lane >> 3;
    const int sslot = lane & 7;

    size_t aOff[4], bOff[4]; int ldsOff[4];
#pragma unroll
    for (int r4 = 0; r4 < 4; ++r4) {
        int rowT = r4 * 32 + wave * 8 + srow;
        int gsl  = (sslot ^ (rowT & 7)) * 8;
        aOff[r4] = (size_t)(row0 + rowT) * 256 + gsl;
        bOff[r4] = (size_t)(n0 + rowT) * 256 + gsl;
        ldsOff[r4] = (r4 * 32 + wave * 8) * BK;
    }

    f32x4 acc[4][4];
#pragma unroll
    for (int i = 0; i < 4; ++i)
#pragma unroll
        for (int jj = 0; jj < 4; ++jj)
#pragma unroll
            for (int r = 0; r < 4; ++r) acc[i][jj][r] = 0.0f;

    for (int kIter = 0; kIter < 4; ++kIter) {
        int k0 = kIter * BK;
        __syncthreads();
#pragma unroll
        for (int r4 = 0; r4 < 4; ++r4)
            gload_lds16(A + aOff[r4] + k0, &As[ldsOff[r4]]);
#pragma unroll
        for (int r4 = 0; r4 < 4; ++r4)
            gload_lds16(W + bOff[r4] + k0, &Bs[ldsOff[r4]]);
        __syncthreads();

#pragma unroll
        for (int kk = 0; kk < BK; kk += 32) {
            const int sl0 = (kk >> 3) + quad;
            bf16x8 af[4], bfr[4];
#pragma unroll
            for (int mi = 0; mi < 4; ++mi) {
                int row = wm * 64 + mi * 16 + l15;
                int ps  = sl0 ^ (row & 7);
                af[mi] = *(const bf16x8*)&As[row * BK + ps * 8];
            }
#pragma unroll
            for (int ni = 0; ni < 4; ++ni) {
                int row = wn * 64 + ni * 16 + l15;
                int ps  = sl0 ^ (row & 7);
                bfr[ni] = *(const bf16x8*)&Bs[row * BK + ps * 8];
            }
#pragma unroll
            for (int mi = 0; mi < 4; ++mi)
#pragma unroll
                for (int ni = 0; ni < 4; ++ni)
                    acc[mi][ni] = __builtin_amdgcn_mfma_f32_16x16x32_bf16(
                        af[mi], bfr[ni], acc[mi][ni], 0, 0, 0);
        }
    }

#pragma unroll
    for (int mi = 0; mi < 4; ++mi) {
#pragma unroll
        for (int ni = 0; ni < 4; ++ni) {
            int n = n0 + wn * 64 + ni * 16 + l15;
            float bv = bias[n];
#pragma unroll
            for (int reg = 0; reg < 4; ++reg) {
                int row = row0 + wm * 64 + mi * 16 + quad * 4 + reg;
                Out[(size_t)row * 256 + n] = acc[mi][ni][reg] + bv;
            }
        }
    }
}

// ---------------------------------------------------------------------------
// Fallback path (verified at 1273 us): fp32 storage, reg-staged bf16 compute.
// Used when ws_size is too small for the bf16 workspace.
// ---------------------------------------------------------------------------

__global__ __launch_bounds__(256, 2) void lstm_cell_kernel(
    const float* __restrict__ A1, const float* __restrict__ A2,
    const float* __restrict__ W1, const float* __restrict__ W2,
    const float* __restrict__ b1, const float* __restrict__ b2,
    const float* __restrict__ Cin,
    float* __restrict__ Hout, float* __restrict__ Cout)
{
    __shared__ __align__(16) bf16 As[BM * BK];
    __shared__ __align__(16) bf16 Bs[BM * BK];

    const int tid  = threadIdx.x;
    const int lane = tid & 63;
    const int wave = tid >> 6;
    const int wm   = wave >> 1;
    const int wn   = wave & 1;
    const int quad = lane >> 4;
    const int l15  = lane & 15;
    const int row0 = blockIdx.x * BM;
    const int jblk = blockIdx.y * 32;

    f32x4 acc[4][4];
#pragma unroll
    for (int i = 0; i < 4; ++i)
#pragma unroll
        for (int jj = 0; jj < 4; ++jj)
#pragma unroll
            for (int r = 0; r < 4; ++r) acc[i][jj][r] = 0.0f;

    for (int kIter = 0; kIter < 8; ++kIter) {
        const float* aSrc; const float* wSrc; int k0;
        if (kIter < 4) { aSrc = A1; wSrc = W1; k0 = kIter * BK; }
        else           { aSrc = A2; wSrc = W2; k0 = (kIter - 4) * BK; }

        __syncthreads();
#pragma unroll
        for (int it = 0; it < 8; ++it) {
            int c = it * 256 + tid;
            int r = c >> 4;
            int kc = c & 15;
            float4 va = *(const float4*)(aSrc + (size_t)(row0 + r) * 256 + k0 + kc * 4);
            *(bf16x4*)&As[r * BK + kc * 4] = cvt4(va);
            int gate = (r >> 4) & 3;
            int j    = jblk + (r & 15) + ((r >> 6) << 4);
            float4 vb = *(const float4*)(wSrc + (size_t)(gate * 256 + j) * 256 + k0 + kc * 4);
            *(bf16x4*)&Bs[r * BK + kc * 4] = cvt4(vb);
        }
        __syncthreads();

#pragma unroll
        for (int kk = 0; kk < BK; kk += 32) {
            bf16x8 af[4], bfr[4];
#pragma unroll
            for (int mi = 0; mi < 4; ++mi)
                af[mi] = *(const bf16x8*)&As[(wm * 64 + mi * 16 + l15) * BK + kk + quad * 8];
#pragma unroll
            for (int ni = 0; ni < 4; ++ni)
                bfr[ni] = *(const bf16x8*)&Bs[(wn * 64 + ni * 16 + l15) * BK + kk + quad * 8];
#pragma unroll
            for (int mi = 0; mi < 4; ++mi)
#pragma unroll
                for (int ni = 0; ni < 4; ++ni)
                    acc[mi][ni] = __builtin_amdgcn_mfma_f32_16x16x32_bf16(
                        af[mi], bfr[ni], acc[mi][ni], 0, 0, 0);
        }
    }

    const int j = jblk + wn * 16 + l15;
    float bsum[4];
#pragma unroll
    for (int g = 0; g < 4; ++g)
        bsum[g] = b1[g * 256 + j] + b2[g * 256 + j];

#pragma unroll
    for (int mi = 0; mi < 4; ++mi) {
#pragma unroll
        for (int reg = 0; reg < 4; ++reg) {
            int row = row0 + wm * 64 + mi * 16 + quad * 4 + reg;
            float gi = acc[mi][0][reg] + bsum[0];
            float gf = acc[mi][1][reg] + bsum[1];
            float gg = acc[mi][2][reg] + bsum[2];
            float go = acc[mi][3][reg] + bsum[3];
            float c  = Cin[(size_t)row * 256 + j];
            float cn = sigmoidf_(gf) * c + sigmoidf_(gi) * tanhf_(gg);
            float hn = sigmoidf_(go) * tanhf_(cn);
            Hout[(size_t)row * 256 + j] = hn;
            Cout[(size_t)row * 256 + j] = cn;
        }
    }
}

__global__ __launch_bounds__(256, 2) void linear_kernel(
    const float* __restrict__ A, const float* __restrict__ W,
    const float* __restrict__ bias, float* __restrict__ Out)
{
    __shared__ __align__(16) bf16 As[BM * BK];
    __shared__ __align__(16) bf16 Bs[BM * BK];

    const int tid  = threadIdx.x;
    const int lane = tid & 63;
    const int wave = tid >> 6;
    const int wm   = wave >> 1;
    const int wn   = wave & 1;
    const int quad = lane >> 4;
    const int l15  = lane & 15;
    const int row0 = blockIdx.x * BM;
    const int n0   = blockIdx.y * 128;

    f32x4 acc[4][4];
#pragma unroll
    for (int i = 0; i < 4; ++i)
#pragma unroll
        for (int jj = 0; jj < 4; ++jj)
#pragma unroll
            for (int r = 0; r < 4; ++r) acc[i][jj][r] = 0.0f;

    for (int kIter = 0; kIter < 4; ++kIter) {
        int k0 = kIter * BK;
        __syncthreads();
#pragma unroll
        for (int it = 0; it < 8; ++it) {
            int c = it * 256 + tid;
            int r = c >> 4, kc = c & 15;
            float4 va = *(const float4*)(A + (size_t)(row0 + r) * 256 + k0 + kc * 4);
            *(bf16x4*)&As[r * BK + kc * 4] = cvt4(va);
            float4 vb = *(const float4*)(W + (size_t)(n0 + r) * 256 + k0 + kc * 4);
            *(bf16x4*)&Bs[r * BK + kc * 4] = cvt4(vb);
        }
        __syncthreads();

#pragma unroll
        for (int kk = 0; kk < BK; kk += 32) {
            bf16x8 af[4], bfr[4];
#pragma unroll
            for (int mi = 0; mi < 4; ++mi)
                af[mi] = *(const bf16x8*)&As[(wm * 64 + mi * 16 + l15) * BK + kk + quad * 8];
#pragma unroll
            for (int ni = 0; ni < 4; ++ni)
                bfr[ni] = *(const bf16x8*)&Bs[(wn * 64 + ni * 16 + l15) * BK + kk + quad * 8];
#pragma unroll
            for (int mi = 0; mi < 4; ++mi)
#pragma unroll
                for (int ni = 0; ni < 4; ++ni)
                    acc[mi][ni] = __builtin_amdgcn_mfma_f32_16x16x32_bf16(
                        af[mi], bfr[ni], acc[mi][ni], 0, 0, 0);
        }
    }

#pragma unroll
    for (int mi = 0; mi < 4; ++mi) {
#pragma unroll
        for (int ni = 0; ni < 4; ++ni) {
            int n = n0 + wn * 64 + ni * 16 + l15;
            float bv = bias[n];
#pragma unroll
            for (int reg = 0; reg < 4; ++reg) {
                int row = row0 + wm * 64 + mi * 16 + quad * 4 + reg;
                Out[(size_t)row * 256 + n] = acc[mi][ni][reg] + bv;
            }
        }
    }
}

extern "C" void kernel_launch(void* const* d_in, const int* in_sizes, int n_in,
                              void* d_out, int out_size, void* d_ws, size_t ws_size,
                              hipStream_t stream) {
    const float* x     = (const float*)d_in[0];
    const float* h_all = (const float*)d_in[1];
    const float* c_all = (const float*)d_in[2];
    const float* Wih0  = (const float*)d_in[3];
    const float* Whh0  = (const float*)d_in[4];
    const float* bih0  = (const float*)d_in[5];
    const float* bhh0  = (const float*)d_in[6];
    const float* Wih   = (const float*)d_in[7];
    const float* Whh   = (const float*)d_in[8];
    const float* bih   = (const float*)d_in[9];
    const float* bhh   = (const float*)d_in[10];
    const float* Wout  = (const float*)d_in[11];
    const float* bout  = (const float*)d_in[12];
    float* out = (float*)d_out;

    float* hs = out + SL;        // hs[l] = hs + l*SL, l = 0..7  (required outputs)
    float* cs = out + SL * 9;    // cs[l] = cs + l*SL

    dim3 block(256);
    dim3 grid(BROWS / BM, 8);

    // bf16 workspace layout (elements):
    //   xb 4,194,304 | hball 33,554,432 | wih0b 262,144 | whh0b 262,144
    //   wihb 1,835,008 | whhb 1,835,008 | woutb 65,536 | hbA 4,194,304 | hbB 4,194,304
    const size_t WS_NEEDED_BYTES = (size_t)50397184 * 2;  // ~96.1 MiB

    if (d_ws != nullptr && ws_size >= WS_NEEDED_BYTES) {
        bf16* wsb   = (bf16*)d_ws;
        bf16* xb    = wsb;
        bf16* hball = xb    + 4194304;
        bf16* wih0b = hball + 33554432;
        bf16* whh0b = wih0b + 262144;
        bf16* wihb  = whh0b + 262144;
        bf16* whhb  = wihb  + 1835008;
        bf16* woutb = whhb  + 1835008;
        bf16* hbA   = woutb + 65536;
        bf16* hbB   = hbA   + 4194304;

        convert_all<<<2048, 256, 0, stream>>>(
            x,     xb,    4194304u  / 4,
            h_all, hball, 33554432u / 4,
            Wih0,  wih0b, 262144u   / 4,
            Whh0,  whh0b, 262144u   / 4,
            Wih,   wihb,  1835008u  / 4,
            Whh,   whhb,  1835008u  / 4,
            Wout,  woutb, 65536u    / 4);

        // cell 0 (input cell)
        lstm_cell_bf16<<<grid, block, 0, stream>>>(
            xb, hball, wih0b, whh0b, bih0, bhh0, c_all, hs, cs, hbA);

        // cells 1..7 — sequential layer recurrence (bf16 h via ping-pong)
        bf16* hprev = hbA; bf16* hcur = hbB;
        for (int l = 1; l <= 7; ++l) {
            lstm_cell_bf16<<<grid, block, 0, stream>>>(
                hprev,
                hball + (size_t)l * SL,
                wihb + (size_t)(l - 1) * 262144,
                whhb + (size_t)(l - 1) * 262144,
                bih + (size_t)(l - 1) * 1024,
                bhh + (size_t)(l - 1) * 1024,
                c_all + (size_t)l * SL,
                hs + (size_t)l * SL,
                cs + (size_t)l * SL,
                hcur);
            bf16* t = hprev; hprev = hcur; hcur = t;
        }

        linear_bf16<<<dim3(BROWS / BM, 2), block, 0, stream>>>(hprev, woutb, bout, out);
    } else {
        // Fallback: verified fp32-storage path (no workspace needed).
        lstm_cell_kernel<<<grid, block, 0, stream>>>(
            x, h_all, Wih0, Whh0, bih0, bhh0, c_all, hs, cs);

        for (int l = 1; l <= 7; ++l) {
            lstm_cell_kernel<<<grid, block, 0, stream>>>(
                hs + (size_t)(l - 1) * SL,
                h_all + (size_t)l * SL,
                Wih + (size_t)(l - 1) * 1024 * 256,
                Whh + (size_t)(l - 1) * 1024 * 256,
                bih + (size_t)(l - 1) * 1024,
                bhh + (size_t)(l - 1) * 1024,
                c_all + (size_t)l * SL,
                hs + (size_t)l * SL,
                cs + (size_t)l * SL);
        }

        linear_kernel<<<dim3(BROWS / BM, 2), block, 0, stream>>>(
            hs + SL * 7, Wout, bout, out);
    }
}

// Round 3
// 741.606 us; speedup vs baseline: 1.7166x; 1.0029x over previous
//
#include <hip/hip_runtime.h>
#include <stdint.h>

typedef __bf16 bf16;
typedef bf16 bf16x8 __attribute__((ext_vector_type(8)));
typedef bf16 bf16x4 __attribute__((ext_vector_type(4)));
typedef float f32x4 __attribute__((ext_vector_type(4)));

#define BROWS 16384
#define BM 128
#define BK 64
#define SL ((size_t)BROWS * 256)

__device__ __forceinline__ float sigmoidf_(float x) { return 1.0f / (1.0f + __expf(-x)); }
__device__ __forceinline__ float tanhf_(float x)    { return 1.0f - 2.0f / (1.0f + __expf(2.0f * x)); }

__device__ __forceinline__ bf16x4 cvt4(float4 v) {
    bf16x4 b; b[0] = (bf16)v.x; b[1] = (bf16)v.y; b[2] = (bf16)v.z; b[3] = (bf16)v.w;
    return b;
}

// Async global->LDS, 16B per lane. LDS dest = wave-uniform base + lane*16 (linear).
__device__ __forceinline__ void gload_lds16(const void* g, void* l) {
    __builtin_amdgcn_global_load_lds(
        (const __attribute__((address_space(1))) void*)g,
        (__attribute__((address_space(3))) void*)l, 16, 0, 0);
}

// ---------------------------------------------------------------------------
// One-time fp32->bf16 conversion of x, h_all, weights into the workspace.
// ---------------------------------------------------------------------------

__global__ void convert_all(
    const float* __restrict__ s0, bf16* __restrict__ d0, unsigned n0,
    const float* __restrict__ s1, bf16* __restrict__ d1, unsigned n1,
    const float* __restrict__ s2, bf16* __restrict__ d2, unsigned n2,
    const float* __restrict__ s3, bf16* __restrict__ d3, unsigned n3,
    const float* __restrict__ s4, bf16* __restrict__ d4, unsigned n4,
    const float* __restrict__ s5, bf16* __restrict__ d5, unsigned n5,
    const float* __restrict__ s6, bf16* __restrict__ d6, unsigned n6)
{
    const unsigned total = n0 + n1 + n2 + n3 + n4 + n5 + n6;
    const unsigned stride = gridDim.x * blockDim.x;
    for (unsigned i = blockIdx.x * blockDim.x + threadIdx.x; i < total; i += stride) {
        unsigned idx = i;
        const float* src; bf16* dst;
        if      (idx < n0)         { src = s0; dst = d0; }
        else if ((idx -= n0) < n1) { src = s1; dst = d1; }
        else if ((idx -= n1) < n2) { src = s2; dst = d2; }
        else if ((idx -= n2) < n3) { src = s3; dst = d3; }
        else if ((idx -= n3) < n4) { src = s4; dst = d4; }
        else if ((idx -= n4) < n5) { src = s5; dst = d5; }
        else                       { idx -= n5; src = s6; dst = d6; }
        float4 v = *(const float4*)(src + (size_t)idx * 4);
        *(bf16x4*)(dst + (size_t)idx * 4) = cvt4(v);
    }
}

// ---------------------------------------------------------------------------
// LSTM cell, pure-bf16 operands, 2-phase double-buffered pipeline (T3 minimum):
//   prologue STAGE(0); each iter: barrier(drain) -> STAGE(t+1) -> COMPUTE(t).
// Next tile's HBM latency hides under current tile's ds_read+MFMA.
// Gate-interleaved tile-col map: tile col t -> gate=(t>>4)&3,
// j = jblk + (t&15) + ((t>>6)<<4); weight row = gate*256 + j.
// XOR swizzle both-sides (rule #21): linear LDS dest, inverse-swizzled global
// source slot, same XOR on ds_read.
// ---------------------------------------------------------------------------

__global__ __launch_bounds__(256, 2) void lstm_cell_bf16(
    const bf16* __restrict__ A1, const bf16* __restrict__ A2,
    const bf16* __restrict__ W1, const bf16* __restrict__ W2,
    const float* __restrict__ b1, const float* __restrict__ b2,
    const float* __restrict__ Cin,
    float* __restrict__ Hout, float* __restrict__ Cout,
    bf16* __restrict__ Hb)
{
    __shared__ __align__(16) bf16 As[2][BM * BK];   // 2 x 16 KB
    __shared__ __align__(16) bf16 Bs[2][BM * BK];   // 2 x 16 KB

    const int tid  = threadIdx.x;
    const int lane = tid & 63;
    const int wave = tid >> 6;
    const int wm   = wave >> 1;          // row half
    const int wn   = wave & 1;           // col half
    const int quad = lane >> 4;
    const int l15  = lane & 15;
    const int row0 = blockIdx.x * BM;
    const int jblk = blockIdx.y * 32;

    // staging lane geometry: each wave covers 8 rows x 8 slots (16B) per issue
    const int srow  = lane >> 3;
    const int sslot = lane & 7;

    size_t aOff[4], bOff[4]; int ldsOff[4];
#pragma unroll
    for (int r4 = 0; r4 < 4; ++r4) {
        int rowT = r4 * 32 + wave * 8 + srow;
        int gsl  = (sslot ^ (rowT & 7)) * 8;          // inverse-swizzled source slot
        aOff[r4] = (size_t)(row0 + rowT) * 256 + gsl;
        int gate = (rowT >> 4) & 3;
        int j    = jblk + (rowT & 15) + ((rowT >> 6) << 4);
        bOff[r4] = (size_t)(gate * 256 + j) * 256 + gsl;
        ldsOff[r4] = (r4 * 32 + wave * 8) * BK;       // linear LDS dest (bf16 elems)
    }

    f32x4 acc[4][4];
#pragma unroll
    for (int i = 0; i < 4; ++i)
#pragma unroll
        for (int jj = 0; jj < 4; ++jj)
#pragma unroll
            for (int r = 0; r < 4; ++r) acc[i][jj][r] = 0.0f;

    auto STAGE = [&](int t, int buf) {
        const bf16* aSrc; const bf16* wSrc; int k0;
        if (t < 4) { aSrc = A1; wSrc = W1; k0 = t * BK; }
        else       { aSrc = A2; wSrc = W2; k0 = (t - 4) * BK; }
#pragma unroll
        for (int r4 = 0; r4 < 4; ++r4) {
            gload_lds16(aSrc + aOff[r4] + k0, &As[buf][ldsOff[r4]]);
            gload_lds16(wSrc + bOff[r4] + k0, &Bs[buf][ldsOff[r4]]);
        }
    };

    auto COMPUTE = [&](int buf) {
#pragma unroll
        for (int kk = 0; kk < BK; kk += 32) {
            const int sl0 = (kk >> 3) + quad;         // logical 16B slot
            bf16x8 af[4], bfr[4];
#pragma unroll
            for (int mi = 0; mi < 4; ++mi) {
                int row = wm * 64 + mi * 16 + l15;
                int ps  = sl0 ^ (row & 7);            // swizzled read slot
                af[mi] = *(const bf16x8*)&As[buf][row * BK + ps * 8];
            }
#pragma unroll
            for (int ni = 0; ni < 4; ++ni) {
                int row = wn * 64 + ni * 16 + l15;
                int ps  = sl0 ^ (row & 7);
                bfr[ni] = *(const bf16x8*)&Bs[buf][row * BK + ps * 8];
            }
#pragma unroll
            for (int mi = 0; mi < 4; ++mi)
#pragma unroll
                for (int ni = 0; ni < 4; ++ni)
                    acc[mi][ni] = __builtin_amdgcn_mfma_f32_16x16x32_bf16(
                        af[mi], bfr[ni], acc[mi][ni], 0, 0, 0);
        }
    };

    STAGE(0, 0);
#pragma unroll
    for (int t = 0; t < 8; ++t) {
        __syncthreads();                  // drains vmcnt(0): tile t is in LDS;
                                          // also: everyone done reading buf t&1 from t-2
        if (t < 7) STAGE(t + 1, (t + 1) & 1);
        COMPUTE(t & 1);                   // hides STAGE(t+1) latency
    }

    // Epilogue: acc[mi][gate][reg] at row = row0+wm*64+mi*16+quad*4+reg, col j.
    const int j = jblk + wn * 16 + l15;
    float bsum[4];
#pragma unroll
    for (int g = 0; g < 4; ++g)
        bsum[g] = b1[g * 256 + j] + b2[g * 256 + j];

#pragma unroll
    for (int mi = 0; mi < 4; ++mi) {
#pragma unroll
        for (int reg = 0; reg < 4; ++reg) {
            int row = row0 + wm * 64 + mi * 16 + quad * 4 + reg;
            float gi = acc[mi][0][reg] + bsum[0];
            float gf = acc[mi][1][reg] + bsum[1];
            float gg = acc[mi][2][reg] + bsum[2];
            float go = acc[mi][3][reg] + bsum[3];
            float c  = Cin[(size_t)row * 256 + j];
            float cn = sigmoidf_(gf) * c + sigmoidf_(gi) * tanhf_(gg);
            float hn = sigmoidf_(go) * tanhf_(cn);
            Hout[(size_t)row * 256 + j] = hn;
            Cout[(size_t)row * 256 + j] = cn;
            Hb[(size_t)row * 256 + j]   = (bf16)hn;   // bf16 copy for next cell
        }
    }
}

// Out[B,256] = A[B,256] @ W[256,256]^T + bias, bf16 operands, 2-phase pipeline.
__global__ __launch_bounds__(256, 2) void linear_bf16(
    const bf16* __restrict__ A, const bf16* __restrict__ W,
    const float* __restrict__ bias, float* __restrict__ Out)
{
    __shared__ __align__(16) bf16 As[2][BM * BK];
    __shared__ __align__(16) bf16 Bs[2][BM * BK];

    const int tid  = threadIdx.x;
    const int lane = tid & 63;
    const int wave = tid >> 6;
    const int wm   = wave >> 1;
    const int wn   = wave & 1;
    const int quad = lane >> 4;
    const int l15  = lane & 15;
    const int row0 = blockIdx.x * BM;
    const int n0   = blockIdx.y * 128;

    const int srow  = lane >> 3;
    const int sslot = lane & 7;

    size_t aOff[4], bOff[4]; int ldsOff[4];
#pragma unroll
    for (int r4 = 0; r4 < 4; ++r4) {
        int rowT = r4 * 32 + wave * 8 + srow;
        int gsl  = (sslot ^ (rowT & 7)) * 8;
        aOff[r4] = (size_t)(row0 + rowT) * 256 + gsl;
        bOff[r4] = (size_t)(n0 + rowT) * 256 + gsl;
        ldsOff[r4] = (r4 * 32 + wave * 8) * BK;
    }

    f32x4 acc[4][4];
#pragma unroll
    for (int i = 0; i < 4; ++i)
#pragma unroll
        for (int jj = 0; jj < 4; ++jj)
#pragma unroll
            for (int r = 0; r < 4; ++r) acc[i][jj][r] = 0.0f;

    auto STAGE = [&](int t, int buf) {
        int k0 = t * BK;
#pragma unroll
        for (int r4 = 0; r4 < 4; ++r4) {
            gload_lds16(A + aOff[r4] + k0, &As[buf][ldsOff[r4]]);
            gload_lds16(W + bOff[r4] + k0, &Bs[buf][ldsOff[r4]]);
        }
    };

    auto COMPUTE = [&](int buf) {
#pragma unroll
        for (int kk = 0; kk < BK; kk += 32) {
            const int sl0 = (kk >> 3) + quad;
            bf16x8 af[4], bfr[4];
#pragma unroll
            for (int mi = 0; mi < 4; ++mi) {
                int row = wm * 64 + mi * 16 + l15;
                int ps  = sl0 ^ (row & 7);
                af[mi] = *(const bf16x8*)&As[buf][row * BK + ps * 8];
            }
#pragma unroll
            for (int ni = 0; ni < 4; ++ni) {
                int row = wn * 64 + ni * 16 + l15;
                int ps  = sl0 ^ (row & 7);
                bfr[ni] = *(const bf16x8*)&Bs[buf][row * BK + ps * 8];
            }
#pragma unroll
            for (int mi = 0; mi < 4; ++mi)
#pragma unroll
                for (int ni = 0; ni < 4; ++ni)
                    acc[mi][ni] = __builtin_amdgcn_mfma_f32_16x16x32_bf16(
                        af[mi], bfr[ni], acc[mi][ni], 0, 0, 0);
        }
    };

    STAGE(0, 0);
#pragma unroll
    for (int t = 0; t < 4; ++t) {
        __syncthreads();
        if (t < 3) STAGE(t + 1, (t + 1) & 1);
        COMPUTE(t & 1);
    }

#pragma unroll
    for (int mi = 0; mi < 4; ++mi) {
#pragma unroll
        for (int ni = 0; ni < 4; ++ni) {
            int n = n0 + wn * 64 + ni * 16 + l15;
            float bv = bias[n];
#pragma unroll
            for (int reg = 0; reg < 4; ++reg) {
                int row = row0 + wm * 64 + mi * 16 + quad * 4 + reg;
                Out[(size_t)row * 256 + n] = acc[mi][ni][reg] + bv;
            }
        }
    }
}

// ---------------------------------------------------------------------------
// Fallback path (verified): fp32 storage, reg-staged bf16 compute.
// Used only if ws_size is too small for the bf16 workspace.
// ---------------------------------------------------------------------------

__global__ __launch_bounds__(256, 2) void lstm_cell_kernel(
    const float* __restrict__ A1, const float* __restrict__ A2,
    const float* __restrict__ W1, const float* __restrict__ W2,
    const float* __restrict__ b1, const float* __restrict__ b2,
    const float* __restrict__ Cin,
    float* __restrict__ Hout, float* __restrict__ Cout)
{
    __shared__ __align__(16) bf16 As[BM * BK];
    __shared__ __align__(16) bf16 Bs[BM * BK];

    const int tid  = threadIdx.x;
    const int lane = tid & 63;
    const int wave = tid >> 6;
    const int wm   = wave >> 1;
    const int wn   = wave & 1;
    const int quad = lane >> 4;
    const int l15  = lane & 15;
    const int row0 = blockIdx.x * BM;
    const int jblk = blockIdx.y * 32;

    f32x4 acc[4][4];
#pragma unroll
    for (int i = 0; i < 4; ++i)
#pragma unroll
        for (int jj = 0; jj < 4; ++jj)
#pragma unroll
            for (int r = 0; r < 4; ++r) acc[i][jj][r] = 0.0f;

    for (int kIter = 0; kIter < 8; ++kIter) {
        const float* aSrc; const float* wSrc; int k0;
        if (kIter < 4) { aSrc = A1; wSrc = W1; k0 = kIter * BK; }
        else           { aSrc = A2; wSrc = W2; k0 = (kIter - 4) * BK; }

        __syncthreads();
#pragma unroll
        for (int it = 0; it < 8; ++it) {
            int c = it * 256 + tid;
            int r = c >> 4;
            int kc = c & 15;
            float4 va = *(const float4*)(aSrc + (size_t)(row0 + r) * 256 + k0 + kc * 4);
            *(bf16x4*)&As[r * BK + kc * 4] = cvt4(va);
            int gate = (r >> 4) & 3;
            int j    = jblk + (r & 15) + ((r >> 6) << 4);
            float4 vb = *(const float4*)(wSrc + (size_t)(gate * 256 + j) * 256 + k0 + kc * 4);
            *(bf16x4*)&Bs[r * BK + kc * 4] = cvt4(vb);
        }
        __syncthreads();

#pragma unroll
        for (int kk = 0; kk < BK; kk += 32) {
            bf16x8 af[4], bfr[4];
#pragma unroll
            for (int mi = 0; mi < 4; ++mi)
                af[mi] = *(const bf16x8*)&As[(wm * 64 + mi * 16 + l15) * BK + kk + quad * 8];
#pragma unroll
            for (int ni = 0; ni < 4; ++ni)
                bfr[ni] = *(const bf16x8*)&Bs[(wn * 64 + ni * 16 + l15) * BK + kk + quad * 8];
#pragma unroll
            for (int mi = 0; mi < 4; ++mi)
#pragma unroll
                for (int ni = 0; ni < 4; ++ni)
                    acc[mi][ni] = __builtin_amdgcn_mfma_f32_16x16x32_bf16(
                        af[mi], bfr[ni], acc[mi][ni], 0, 0, 0);
        }
    }

    const int j = jblk + wn * 16 + l15;
    float bsum[4];
#pragma unroll
    for (int g = 0; g < 4; ++g)
        bsum[g] = b1[g * 256 + j] + b2[g * 256 + j];

#pragma unroll
    for (int mi = 0; mi < 4; ++mi) {
#pragma unroll
        for (int reg = 0; reg < 4; ++reg) {
            int row = row0 + wm * 64 + mi * 16 + quad * 4 + reg;
            float gi = acc[mi][0][reg] + bsum[0];
            float gf = acc[mi][1][reg] + bsum[1];
            float gg = acc[mi][2][reg] + bsum[2];
            float go = acc[mi][3][reg] + bsum[3];
            float c  = Cin[(size_t)row * 256 + j];
            float cn = sigmoidf_(gf) * c + sigmoidf_(gi) * tanhf_(gg);
            float hn = sigmoidf_(go) * tanhf_(cn);
            Hout[(size_t)row * 256 + j] = hn;
            Cout[(size_t)row * 256 + j] = cn;
        }
    }
}

__global__ __launch_bounds__(256, 2) void linear_kernel(
    const float* __restrict__ A, const float* __restrict__ W,
    const float* __restrict__ bias, float* __restrict__ Out)
{
    __shared__ __align__(16) bf16 As[BM * BK];
    __shared__ __align__(16) bf16 Bs[BM * BK];

    const int tid  = threadIdx.x;
    const int lane = tid & 63;
    const int wave = tid >> 6;
    const int wm   = wave >> 1;
    const int wn   = wave & 1;
    const int quad = lane >> 4;
    const int l15  = lane & 15;
    const int row0 = blockIdx.x * BM;
    const int n0   = blockIdx.y * 128;

    f32x4 acc[4][4];
#pragma unroll
    for (int i = 0; i < 4; ++i)
#pragma unroll
        for (int jj = 0; jj < 4; ++jj)
#pragma unroll
            for (int r = 0; r < 4; ++r) acc[i][jj][r] = 0.0f;

    for (int kIter = 0; kIter < 4; ++kIter) {
        int k0 = kIter * BK;
        __syncthreads();
#pragma unroll
        for (int it = 0; it < 8; ++it) {
            int c = it * 256 + tid;
            int r = c >> 4, kc = c & 15;
            float4 va = *(const float4*)(A + (size_t)(row0 + r) * 256 + k0 + kc * 4);
            *(bf16x4*)&As[r * BK + kc * 4] = cvt4(va);
            float4 vb = *(const float4*)(W + (size_t)(n0 + r) * 256 + k0 + kc * 4);
            *(bf16x4*)&Bs[r * BK + kc * 4] = cvt4(vb);
        }
        __syncthreads();

#pragma unroll
        for (int kk = 0; kk < BK; kk += 32) {
            bf16x8 af[4], bfr[4];
#pragma unroll
            for (int mi = 0; mi < 4; ++mi)
                af[mi] = *(const bf16x8*)&As[(wm * 64 + mi * 16 + l15) * BK + kk + quad * 8];
#pragma unroll
            for (int ni = 0; ni < 4; ++ni)
                bfr[ni] = *(const bf16x8*)&Bs[(wn * 64 + ni * 16 + l15) * BK + kk + quad * 8];
#pragma unroll
            for (int mi = 0; mi < 4; ++mi)
#pragma unroll
                for (int ni = 0; ni < 4; ++ni)
                    acc[mi][ni] = __builtin_amdgcn_mfma_f32_16x16x32_bf16(
                        af[mi], bfr[ni], acc[mi][ni], 0, 0, 0);
        }
    }

#pragma unroll
    for (int mi = 0; mi < 4; ++mi) {
#pragma unroll
        for (int ni = 0; ni < 4; ++ni) {
            int n = n0 + wn * 64 + ni * 16 + l15;
            float bv = bias[n];
#pragma unroll
            for (int reg = 0; reg < 4; ++reg) {
                int row = row0 + wm * 64 + mi * 16 + quad * 4 + reg;
                Out[(size_t)row * 256 + n] = acc[mi][ni][reg] + bv;
            }
        }
    }
}

extern "C" void kernel_launch(void* const* d_in, const int* in_sizes, int n_in,
                              void* d_out, int out_size, void* d_ws, size_t ws_size,
                              hipStream_t stream) {
    const float* x     = (const float*)d_in[0];
    const float* h_all = (const float*)d_in[1];
    const float* c_all = (const float*)d_in[2];
    const float* Wih0  = (const float*)d_in[3];
    const float* Whh0  = (const float*)d_in[4];
    const float* bih0  = (const float*)d_in[5];
    const float* bhh0  = (const float*)d_in[6];
    const float* Wih   = (const float*)d_in[7];
    const float* Whh   = (const float*)d_in[8];
    const float* bih   = (const float*)d_in[9];
    const float* bhh   = (const float*)d_in[10];
    const float* Wout  = (const float*)d_in[11];
    const float* bout  = (const float*)d_in[12];
    float* out = (float*)d_out;

    float* hs = out + SL;        // hs[l] = hs + l*SL, l = 0..7  (required outputs)
    float* cs = out + SL * 9;    // cs[l] = cs + l*SL

    dim3 block(256);
    dim3 grid(BROWS / BM, 8);

    // bf16 workspace layout (elements):
    //   xb 4,194,304 | hball 33,554,432 | wih0b 262,144 | whh0b 262,144
    //   wihb 1,835,008 | whhb 1,835,008 | woutb 65,536 | hbA 4,194,304 | hbB 4,194,304
    const size_t WS_NEEDED_BYTES = (size_t)50397184 * 2;  // ~96.1 MiB

    if (d_ws != nullptr && ws_size >= WS_NEEDED_BYTES) {
        bf16* wsb   = (bf16*)d_ws;
        bf16* xb    = wsb;
        bf16* hball = xb    + 4194304;
        bf16* wih0b = hball + 33554432;
        bf16* whh0b = wih0b + 262144;
        bf16* wihb  = whh0b + 262144;
        bf16* whhb  = wihb  + 1835008;
        bf16* woutb = whhb  + 1835008;
        bf16* hbA   = woutb + 65536;
        bf16* hbB   = hbA   + 4194304;

        convert_all<<<2048, 256, 0, stream>>>(
            x,     xb,    4194304u  / 4,
            h_all, hball, 33554432u / 4,
            Wih0,  wih0b, 262144u   / 4,
            Whh0,  whh0b, 262144u   / 4,
            Wih,   wihb,  1835008u  / 4,
            Whh,   whhb,  1835008u  / 4,
            Wout,  woutb, 65536u    / 4);

        // cell 0 (input cell)
        lstm_cell_bf16<<<grid, block, 0, stream>>>(
            xb, hball, wih0b, whh0b, bih0, bhh0, c_all, hs, cs, hbA);

        // cells 1..7 — sequential layer recurrence (bf16 h via ping-pong)
        bf16* hprev = hbA; bf16* hcur = hbB;
        for (int l = 1; l <= 7; ++l) {
            lstm_cell_bf16<<<grid, block, 0, stream>>>(
                hprev,
                hball + (size_t)l * SL,
                wihb + (size_t)(l - 1) * 262144,
                whhb + (size_t)(l - 1) * 262144,
                bih + (size_t)(l - 1) * 1024,
                bhh + (size_t)(l - 1) * 1024,
                c_all + (size_t)l * SL,
                hs + (size_t)l * SL,
                cs + (size_t)l * SL,
                hcur);
            bf16* t = hprev; hprev = hcur; hcur = t;
        }

        linear_bf16<<<dim3(BROWS / BM, 2), block, 0, stream>>>(hprev, woutb, bout, out);
    } else {
        // Fallback: verified fp32-storage path (no workspace needed).
        lstm_cell_kernel<<<grid, block, 0, stream>>>(
            x, h_all, Wih0, Whh0, bih0, bhh0, c_all, hs, cs);

        for (int l = 1; l <= 7; ++l) {
            lstm_cell_kernel<<<grid, block, 0, stream>>>(
                hs + (size_t)(l - 1) * SL,
                h_all + (size_t)l * SL,
                Wih + (size_t)(l - 1) * 1024 * 256,
                Whh + (size_t)(l - 1) * 1024 * 256,
                bih + (size_t)(l - 1) * 1024,
                bhh + (size_t)(l - 1) * 1024,
                c_all + (size_t)l * SL,
                hs + (size_t)l * SL,
                cs + (size_t)l * SL);
        }

        linear_kernel<<<dim3(BROWS / BM, 2), block, 0, stream>>>(
            hs + SL * 7, Wout, bout, out);
    }
}